// Round 8
// baseline (97.579 us; speedup 1.0000x reference)
//
#include <hip/hip_runtime.h>

// Batched 10-qubit statevector simulator — one 64-lane wave per sample.
// State: 1024 complex amps; s = (r<<6)|lane; qubit q <-> bit (9-q):
//   qubits 0..3 -> register-index bits (16 complex float2 per lane)
//   qubits 4..9 -> lane bits (butterfly exchanges)
// Per layer per qubit, RY(a)RZ(b)RZ(g)RY(d) fuse into one SU(2)
// U = [[u, -conj(v)],[v, conj(u)]], p=(b+g)/2.
// R1/R2: 50 gate coefficient sets lane-parallel, broadcast via v_readlane.
// R3: __launch_bounds__(256,4); CNOT chain (3,4)..(8,9) fused to one
//     ds_bpermute pass (dest lane d pulls s = (d^(d>>1)) ^ ((r&1)<<5)).
// R4: float2 state -> VOP3P v_pk_fma_f32.
// R5: masks 1,2 (quad_perm) and 8 (row_ror:8) via DPP on the VALU pipe.
// R6/R7: masks 16/32 via gfx950 v_permlane{16,32}_swap_b32: swapping a
//     REGISTER PAIR re-packs (bit=0,bit=1) amplitude pairs lane-aligned,
//     turning the lane butterfly into a pure register-pair gate (no
//     cndmask), then a second swap restores layout. 64 DS-ops/layer -> VALU.
//     R7 fixes R6's compile error (vector elements can't bind to float& —
//     go through local float temps).

constexpr int NQ  = 10;
constexpr int NL  = 5;
constexpr int OBS = 10;

typedef float f2 __attribute__((ext_vector_type(2)));

#if defined(__has_builtin)
# if __has_builtin(__builtin_amdgcn_permlane16_swap) && \
     __has_builtin(__builtin_amdgcn_permlane32_swap)
#  define USE_PLSWAP 1
# endif
#endif

__device__ __forceinline__ float readlane_f(float v, int l) {
    return __int_as_float(__builtin_amdgcn_readlane(__float_as_int(v), l));
}
__device__ __forceinline__ float bperm_f(int byte_addr, float v) {
    return __int_as_float(__builtin_amdgcn_ds_bpermute(byte_addr, __float_as_int(v)));
}
template <int CTRL>
__device__ __forceinline__ float dpp_f(float v) {
    return __int_as_float(__builtin_amdgcn_update_dpp(
        0, __float_as_int(v), CTRL, 0xF, 0xF, true));
}
#ifdef USE_PLSWAP
// swap halves of a register pair across lanes; returns via out-params by value
__device__ __forceinline__ void plswap16_v(f2 &A, f2 &B) {
    float ax = A.x, bx = B.x, ay = A.y, by = B.y;
    auto rx = __builtin_amdgcn_permlane16_swap(__float_as_uint(ax),
                                               __float_as_uint(bx), false, false);
    auto ry = __builtin_amdgcn_permlane16_swap(__float_as_uint(ay),
                                               __float_as_uint(by), false, false);
    A.x = __uint_as_float(rx[0]); B.x = __uint_as_float(rx[1]);
    A.y = __uint_as_float(ry[0]); B.y = __uint_as_float(ry[1]);
}
__device__ __forceinline__ void plswap32_v(f2 &A, f2 &B) {
    float ax = A.x, bx = B.x, ay = A.y, by = B.y;
    auto rx = __builtin_amdgcn_permlane32_swap(__float_as_uint(ax),
                                               __float_as_uint(bx), false, false);
    auto ry = __builtin_amdgcn_permlane32_swap(__float_as_uint(ay),
                                               __float_as_uint(by), false, false);
    A.x = __uint_as_float(rx[0]); B.x = __uint_as_float(rx[1]);
    A.y = __uint_as_float(ry[0]); B.y = __uint_as_float(ry[1]);
}
#endif
// xor-exchange across lanes; M constant after unroll -> branches fold.
__device__ __forceinline__ float xor_lane(float v, int M,
                                          int a4, int a16, int a32) {
    switch (M) {
    case 1:  return dpp_f<0xB1>(v);          // quad_perm [1,0,3,2]
    case 2:  return dpp_f<0x4E>(v);          // quad_perm [2,3,0,1]
    case 8:  return dpp_f<0x128>(v);         // row_ror:8 == lane^8
    case 4:  return bperm_f(a4,  v);
    case 16: return bperm_f(a16, v);
    default: return bperm_f(a32, v);         // 32
    }
}

__global__ __launch_bounds__(256, 4) void qsim_kernel(
    const float* __restrict__ x,       // (B, 10)
    const float* __restrict__ isc,     // (5, 20)
    const float* __restrict__ w,       // (5, 20)
    const float* __restrict__ oscale,  // (4)
    float* __restrict__ out,           // (B, 4)
    int B)
{
    const int lane = threadIdx.x & 63;
    const int wid  = (blockIdx.x * blockDim.x + threadIdx.x) >> 6;
    if (wid >= B) return;

    // ---- lane-parallel gate-coefficient computation (gates 0..49) ----
    float cUR, cUI, cVR, cVI;
    {
        const int g   = (lane < 50) ? lane : 49;
        const int q   = g % 10;
        const int lyr = g / 10;
        const float xq    = x[wid * OBS + q];
        const float alpha = isc[lyr * 2 * NQ + q]      * xq;
        const float beta  = isc[lyr * 2 * NQ + NQ + q] * xq;
        const float gamma = w[lyr * 2 * NQ + q];
        const float delta = w[lyr * 2 * NQ + NQ + q];
        float sa, ca, sp, cp, sd, cd;
        __sincosf(0.5f * alpha,          &sa, &ca);
        __sincosf(0.5f * (beta + gamma), &sp, &cp);
        __sincosf(0.5f * delta,          &sd, &cd);
        const float A = cd * ca, Bt = sd * sa;
        const float C = cd * sa, D  = sd * ca;
        cUR = (A - Bt) * cp;
        cUI = -(A + Bt) * sp;
        cVR = (C + D) * cp;
        cVI = (C - D) * sp;
    }

    // hoisted bpermute byte-addresses (loop-invariant)
    const int a4  = (lane ^ 4)  * 4;
    const int a16 = (lane ^ 16) * 4;
    const int a32 = (lane ^ 32) * 4;
    const int cnot_src  = (lane ^ (lane >> 1));
    const int addr_even = cnot_src * 4;            // r bit0 == 0
    const int addr_odd  = (cnot_src ^ 32) * 4;     // r bit0 == 1 (CNOT(3,4))

    f2 c[16];
#pragma unroll
    for (int r = 0; r < 16; ++r) c[r] = (f2){0.f, 0.f};
    c[0].x = (lane == 0) ? 1.f : 0.f;   // |0...0>

#define SWAPR(i, j) { f2 _t = c[i]; c[i] = c[j]; c[j] = _t; }

    for (int layer = 0; layer < NL; ++layer) {
        const int base = layer * NQ;   // wave-uniform

        // ---- fused single-qubit unitaries, one per qubit ----
#pragma unroll
        for (int q = 0; q < NQ; ++q) {
            const float ur = readlane_f(cUR, base + q);
            const float ui = readlane_f(cUI, base + q);
            const float vr = readlane_f(cVR, base + q);
            const float vi = readlane_f(cVI, base + q);
            // packed SU(2) constants (unused ones DCE'd per unrolled q)
            const f2 kUU  = {ur, ur};
            const f2 kUIm = {-ui, ui};
            const f2 kVVn = {-vr, -vr};
            const f2 kVV  = {vr, vr};
            const f2 kVIm = {-vi, vi};
            const f2 kUIp = {ui, -ui};

            if (q < 4) {
                // register-bit qubit: pair stride m inside the lane.
                const int m = 1 << (3 - q);
#pragma unroll
                for (int r0 = 0; r0 < 16; ++r0) {
                    if (r0 & m) continue;
                    const int r1 = r0 | m;
                    const f2 c0 = c[r0], c1 = c[r1];
                    const f2 c0s = c0.yx, c1s = c1.yx;
                    c[r0] = kUU*c0 + kUIm*c0s + kVVn*c1 + kVIm*c1s;
                    c[r1] = kVV*c0 + kVIm*c0s + kUU*c1  + kUIp*c1s;
                }
            }
#ifdef USE_PLSWAP
            else if (q == 4 || q == 5) {
                // lane-bit qubit via permlane swap: pack (bit0,bit1) pairs
                // lane-aligned across a register pair, apply pure pair gate,
                // swap back. No lane-dependent signs needed.
#pragma unroll
                for (int r = 0; r < 16; r += 2) {
                    if (q == 4) plswap32_v(c[r], c[r+1]);
                    else        plswap16_v(c[r], c[r+1]);
                    const f2 A = c[r], Bv = c[r+1];
                    const f2 As = A.yx, Bs = Bv.yx;
                    c[r]   = kUU*A + kUIm*As + kVVn*Bv + kVIm*Bs;
                    c[r+1] = kVV*A + kVIm*As + kUU*Bv  + kUIp*Bs;
                    if (q == 4) plswap32_v(c[r], c[r+1]);
                    else        plswap16_v(c[r], c[r+1]);
                }
            }
#endif
            else {
                // lane-bit qubit: butterfly exchange with lane^M.
                const int  M   = 1 << (9 - q);
                const bool bit = (lane & M) != 0;
                const float Pi = bit ? -ui : ui;
                const float Qr = bit ?  vr : -vr;
                const f2 kUUb = {ur, ur};
                const f2 kPI  = {-Pi, Pi};
                const f2 kQR  = {Qr, Qr};
                const f2 kVIb = {-vi, vi};
#pragma unroll
                for (int r = 0; r < 16; ++r) {
                    const f2 mv = c[r];
                    f2 pv;
                    pv.x = xor_lane(mv.x, M, a4, a16, a32);
                    pv.y = xor_lane(mv.y, M, a4, a16, a32);
                    c[r] = kUUb*mv + kPI*mv.yx + kQR*pv + kVIb*pv.yx;
                }
            }
        }

        // ---- CNOT ring: (0,1),(1,2),...,(8,9),(9,0), sequential ----
        // CNOT(0,1): ctrl r-bit3, tgt r-bit2 -> register swap
        SWAPR(8, 12) SWAPR(9, 13) SWAPR(10, 14) SWAPR(11, 15)
        // CNOT(1,2): ctrl r-bit2, tgt r-bit1
        SWAPR(4, 6)  SWAPR(5, 7)  SWAPR(12, 14) SWAPR(13, 15)
        // CNOT(2,3): ctrl r-bit1, tgt r-bit0
        SWAPR(2, 3)  SWAPR(6, 7)  SWAPR(10, 11) SWAPR(14, 15)
        // CNOT(3,4)..(8,9) fused: one bpermute per 32-bit value.
#pragma unroll
        for (int r = 0; r < 16; ++r) {
            const int addr = (r & 1) ? addr_odd : addr_even;
            c[r].x = bperm_f(addr, c[r].x);
            c[r].y = bperm_f(addr, c[r].y);
        }
        // CNOT(9,0): ctrl lane-bit0, tgt r-bit3 -> conditional register swap
        {
            const bool ctl = (lane & 1) != 0;
#pragma unroll
            for (int r = 0; r < 8; ++r) {
                const f2 t0 = c[r], t1 = c[r + 8];
                c[r]     = ctl ? t1 : t0;
                c[r + 8] = ctl ? t0 : t1;
            }
        }
    }

    // ---- <Z_i> for qubits 0..3 (all register bits) ----
    float z0 = 0.f, z1 = 0.f, z2 = 0.f, z3 = 0.f;
#pragma unroll
    for (int r = 0; r < 16; ++r) {
        const float pv = c[r].x * c[r].x + c[r].y * c[r].y;
        z0 += (r & 8) ? -pv : pv;
        z1 += (r & 4) ? -pv : pv;
        z2 += (r & 2) ? -pv : pv;
        z3 += (r & 1) ? -pv : pv;
    }
#pragma unroll
    for (int m = 1; m < 64; m <<= 1) {
        z0 += xor_lane(z0, m, a4, a16, a32);
        z1 += xor_lane(z1, m, a4, a16, a32);
        z2 += xor_lane(z2, m, a4, a16, a32);
        z3 += xor_lane(z3, m, a4, a16, a32);
    }
    if (lane == 0) {
        out[wid * 4 + 0] = z0 * oscale[0];
        out[wid * 4 + 1] = z1 * oscale[1];
        out[wid * 4 + 2] = z2 * oscale[2];
        out[wid * 4 + 3] = z3 * oscale[3];
    }
#undef SWAPR
}

extern "C" void kernel_launch(void* const* d_in, const int* in_sizes, int n_in,
                              void* d_out, int out_size, void* d_ws, size_t ws_size,
                              hipStream_t stream) {
    const float* x      = (const float*)d_in[0];
    const float* isc    = (const float*)d_in[1];
    const float* w      = (const float*)d_in[2];
    const float* oscale = (const float*)d_in[3];
    float* out = (float*)d_out;

    const int B = in_sizes[0] / OBS;             // 4096
    const int threads = 256;                     // 4 waves -> 4 samples per block
    const int blocks = (B * 64 + threads - 1) / threads;
    qsim_kernel<<<blocks, threads, 0, stream>>>(x, isc, w, oscale, out, B);
}